// Round 5
// baseline (193.008 us; speedup 1.0000x reference)
//
#include <hip/hip_runtime.h>
#include <math.h>
#include <float.h>

// Problem constants (match reference)
#define BATCH 4
#define KCLS 16
#define NSRC 4096
#define NTGT 16384

#define TPB 64                       // targets per block
#define STRIPES 4                    // waves per block, each scans NSRC/STRIPES sources
#define SRC_PER_STRIPE (NSRC / STRIPES)  // 1024

// Kernel 1: per-source gate = sigmoid(max_k logits[b,k,s]); pack (sx,sy,sz,ss)
// ss replicates numpy's fp32 order: elementwise squares (rounded), then
// sequential sum ((x2+y2)+z2) — np.sum over a length-3 axis is sequential,
// and the squares are materialized temporaries so no FMA is possible there.
__global__ __launch_bounds__(256) void prep_kernel(
    const float* __restrict__ sem_logits,   // [B, K, NS]
    const float* __restrict__ source_pos,   // [B, 3, NS]
    float4* __restrict__ src4,              // [B*NS] (x,y,z,ss)
    float* __restrict__ gate)               // [B*NS]
{
    int gid = blockIdx.x * blockDim.x + threadIdx.x;   // 0 .. B*NS-1
    int b = gid / NSRC;
    int s = gid - b * NSRC;

    const float* lp = sem_logits + (size_t)b * KCLS * NSRC + s;
    float m = lp[0];
#pragma unroll
    for (int k = 1; k < KCLS; ++k) m = fmaxf(m, lp[(size_t)k * NSRC]);
    gate[gid] = 1.0f / (1.0f + expf(-m));

    const float* sp = source_pos + (size_t)b * 3 * NSRC + s;
    float sx = sp[0], sy = sp[NSRC], sz = sp[2 * NSRC];
    float ss = __fadd_rn(__fadd_rn(__fmul_rn(sx, sx), __fmul_rn(sy, sy)),
                         __fmul_rn(sz, sz));
    src4[gid] = make_float4(sx, sy, sz, ss);
}

// Kernel 2: per-target argmin over sources, replicating the np reference's
// fp32 expanded-form numerics. The ONE change vs R4: the einsum dot is an
// FMA accumulation chain (numpy einsum under -ffp-contract=fast / BLAS
// sgemm K-loop):  acc = rn(t0*s0); acc = fma(t1,s1,acc); acc = fma(t2,s2,acc)
// then d2 = rn( rn(tt + ss) - rn(2*acc) ).
// Block = 256: lane = target (64/block), wave = source stripe.
__global__ __launch_bounds__(256) void nn_gate_kernel(
    const float4* __restrict__ src4,        // [B*NS]
    const float* __restrict__ gate,         // [B*NS]
    const float* __restrict__ target_pos,   // [B, 3, NT]
    float* __restrict__ out)                // [B*NT]
{
    int tid = threadIdx.x;
    int lane = tid & (TPB - 1);     // target within block
    int stripe = tid >> 6;          // 0..3 (one wave per stripe)

    const int blocksPerBatch = NTGT / TPB;  // 256
    int b = blockIdx.x / blocksPerBatch;
    int t = (blockIdx.x - b * blocksPerBatch) * TPB + lane;

    const float* tp = target_pos + (size_t)b * 3 * NTGT + t;
    float tx = tp[0], ty = tp[NTGT], tz = tp[2 * NTGT];
    // tt: squares rounded individually, then sequential sum (np order)
    float tt = __fadd_rn(__fadd_rn(__fmul_rn(tx, tx), __fmul_rn(ty, ty)),
                         __fmul_rn(tz, tz));

    // Wave-uniform source pointer: loop index is uniform -> scalar loads.
    const float4* sp = src4 + (size_t)b * NSRC + stripe * SRC_PER_STRIPE;

    float best = FLT_MAX;
    int bi = 0;
    for (int i = 0; i < SRC_PER_STRIPE; ++i) {
        float4 f = sp[i];
        // FMA accumulation chain over d = 0,1,2 (the R5 hypothesis):
        float acc = __fmul_rn(tx, f.x);            // fma(t0,s0,0) == rn(t0*s0)
        acc = __fmaf_rn(ty, f.y, acc);
        acc = __fmaf_rn(tz, f.z, acc);
        float two_dot = __fadd_rn(acc, acc);       // 2.0*dot (exact)
        float a = __fadd_rn(tt, f.w);              // rn(tt + ss)
        float d2 = __fsub_rn(a, two_dot);          // rn((tt+ss) - 2*dot)
        // strict '<' keeps the FIRST minimum (matches np.argmin tie-break)
        if (d2 < best) { best = d2; bi = i; }
    }
    int bidx = stripe * SRC_PER_STRIPE + bi;

    __shared__ float smin[STRIPES][TPB];
    __shared__ int   sidx[STRIPES][TPB];
    smin[stripe][lane] = best;
    sidx[stripe][lane] = bidx;
    __syncthreads();

    if (stripe == 0) {
        float m = smin[0][lane];
        int mi = sidx[0][lane];
#pragma unroll
        for (int j = 1; j < STRIPES; ++j) {
            float mj = smin[j][lane];
            int ij = sidx[j][lane];
            // lexicographic (value, index): earliest global index wins on ties
            if (mj < m || (mj == m && ij < mi)) { m = mj; mi = ij; }
        }
        out[(size_t)b * NTGT + t] = gate[(size_t)b * NSRC + mi];
    }
}

extern "C" void kernel_launch(void* const* d_in, const int* in_sizes, int n_in,
                              void* d_out, int out_size, void* d_ws, size_t ws_size,
                              hipStream_t stream) {
    const float* sem_logits = (const float*)d_in[0];   // [B,K,NS] fp32
    const float* source_pos = (const float*)d_in[1];   // [B,3,NS] fp32
    const float* target_pos = (const float*)d_in[2];   // [B,3,NT] fp32
    float* out = (float*)d_out;                        // [B,NT,1] fp32

    // workspace layout: src4 (B*NS float4 = 256 KB) | gate (B*NS float = 64 KB)
    float4* src4 = (float4*)d_ws;
    float* gate = (float*)((char*)d_ws + sizeof(float4) * BATCH * NSRC);

    prep_kernel<<<(BATCH * NSRC) / 256, 256, 0, stream>>>(sem_logits, source_pos, src4, gate);
    nn_gate_kernel<<<BATCH * (NTGT / TPB), 256, 0, stream>>>(src4, gate, target_pos, out);
}

// Round 6
// 111.917 us; speedup vs baseline: 1.7246x; 1.7246x over previous
//
#include <hip/hip_runtime.h>
#include <math.h>
#include <float.h>

// Problem constants (match reference)
#define BATCH 4
#define KCLS 16
#define NSRC 4096
#define NTGT 16384

// kernel-2 geometry: 512 threads = 8 waves (source stripes), 2 targets/lane
#define K2_THREADS 512
#define K2_WAVES 8
#define K2_TGT_PER_BLOCK 128                    // 64 lanes * 2 targets
#define K2_SRC_PER_STRIPE (NSRC / K2_WAVES)     // 512

// Kernel 1: per-source gate = sigmoid(max_k logits[b,k,s]); pack (sx,sy,sz,ss).
// ss replicates numpy fp32 order: squares rounded individually, sequential sum.
__global__ __launch_bounds__(64) void prep_kernel(
    const float* __restrict__ sem_logits,   // [B, K, NS]
    const float* __restrict__ source_pos,   // [B, 3, NS]
    float4* __restrict__ src4,              // [B*NS] (x,y,z,ss)
    float* __restrict__ gate)               // [B*NS]
{
    int gid = blockIdx.x * blockDim.x + threadIdx.x;   // 0 .. B*NS-1
    int b = gid / NSRC;
    int s = gid - b * NSRC;

    const float* lp = sem_logits + (size_t)b * KCLS * NSRC + s;
    float m = lp[0];
#pragma unroll
    for (int k = 1; k < KCLS; ++k) m = fmaxf(m, lp[(size_t)k * NSRC]);
    gate[gid] = 1.0f / (1.0f + expf(-m));

    const float* sp = source_pos + (size_t)b * 3 * NSRC + s;
    float sx = sp[0], sy = sp[NSRC], sz = sp[2 * NSRC];
    float ss = __fadd_rn(__fadd_rn(__fmul_rn(sx, sx), __fmul_rn(sy, sy)),
                         __fmul_rn(sz, sz));
    src4[gid] = make_float4(sx, sy, sz, ss);
}

// Kernel 2: per-target argmin, bit-exact np numerics (verified absmax=0.0 in R5):
//   dot = fma-chain: rn(tx*sx); fma(ty,sy,·); fma(tz,sz,·)
//   d2  = fma(-2, dot, rn(tt+ss))   [== rn(rn(tt+ss) - rn(2*dot)), 2*dot exact]
// Block: 512 threads. All 8 waves cover the SAME 128 targets (2/lane); wave w
// scans source stripe [w*512,(w+1)*512) from LDS (broadcast ds_read_b128).
// LDS: 64 KB source stage, aliased after the loop as the 8-way reduce scratch.
__global__ __launch_bounds__(K2_THREADS) void nn_gate_kernel(
    const float4* __restrict__ src4,        // [B*NS]
    const float* __restrict__ gate,         // [B*NS]
    const float* __restrict__ target_pos,   // [B, 3, NT]
    float* __restrict__ out)                // [B*NT]
{
    __shared__ float4 ls[NSRC];             // 64 KB (exactly the static limit)

    int tid = threadIdx.x;
    int lane = tid & 63;
    int wave = tid >> 6;                    // source stripe 0..7

    const int blocksPerBatch = NTGT / K2_TGT_PER_BLOCK;  // 128
    int b = blockIdx.x / blocksPerBatch;
    int tbase = (blockIdx.x - b * blocksPerBatch) * K2_TGT_PER_BLOCK;

    // stage all 4096 sources of this batch into LDS (coalesced float4)
    const float4* gsrc = src4 + (size_t)b * NSRC;
#pragma unroll
    for (int i = 0; i < NSRC / K2_THREADS; ++i)
        ls[tid + i * K2_THREADS] = gsrc[tid + i * K2_THREADS];

    // two targets per lane: t0 = tbase+lane, t1 = tbase+64+lane
    const float* tp = target_pos + (size_t)b * 3 * NTGT;
    int t0 = tbase + lane, t1 = tbase + 64 + lane;
    float tx0 = tp[t0], ty0 = tp[NTGT + t0], tz0 = tp[2 * NTGT + t0];
    float tx1 = tp[t1], ty1 = tp[NTGT + t1], tz1 = tp[2 * NTGT + t1];
    float tt0 = __fadd_rn(__fadd_rn(__fmul_rn(tx0, tx0), __fmul_rn(ty0, ty0)),
                          __fmul_rn(tz0, tz0));
    float tt1 = __fadd_rn(__fadd_rn(__fmul_rn(tx1, tx1), __fmul_rn(ty1, ty1)),
                          __fmul_rn(tz1, tz1));

    __syncthreads();

    const int ibase = wave * K2_SRC_PER_STRIPE;
    float best0 = FLT_MAX, best1 = FLT_MAX;
    int bi0 = 0, bi1 = 0;
#pragma unroll 4
    for (int i = 0; i < K2_SRC_PER_STRIPE; ++i) {
        float4 f = ls[ibase + i];           // wave-uniform -> LDS broadcast
        // target 0
        float acc0 = __fmul_rn(tx0, f.x);
        acc0 = __fmaf_rn(ty0, f.y, acc0);
        acc0 = __fmaf_rn(tz0, f.z, acc0);
        float d20 = __fmaf_rn(-2.0f, acc0, __fadd_rn(tt0, f.w));
        if (d20 < best0) { best0 = d20; bi0 = i; }   // strict '<': first wins
        // target 1
        float acc1 = __fmul_rn(tx1, f.x);
        acc1 = __fmaf_rn(ty1, f.y, acc1);
        acc1 = __fmaf_rn(tz1, f.z, acc1);
        float d21 = __fmaf_rn(-2.0f, acc1, __fadd_rn(tt1, f.w));
        if (d21 < best1) { best1 = d21; bi1 = i; }
    }

    __syncthreads();                        // everyone done READING ls

    // alias ls as reduce scratch: smin[8][128] (4 KB) | sidx[8][128] (4 KB)
    float* smin = (float*)ls;
    int* sidx = (int*)ls + K2_WAVES * K2_TGT_PER_BLOCK;
    smin[wave * K2_TGT_PER_BLOCK + lane] = best0;
    sidx[wave * K2_TGT_PER_BLOCK + lane] = ibase + bi0;
    smin[wave * K2_TGT_PER_BLOCK + 64 + lane] = best1;
    sidx[wave * K2_TGT_PER_BLOCK + 64 + lane] = ibase + bi1;
    __syncthreads();

    if (tid < K2_TGT_PER_BLOCK) {
        float m = smin[tid];
        int mi = sidx[tid];
#pragma unroll
        for (int j = 1; j < K2_WAVES; ++j) {
            float mj = smin[j * K2_TGT_PER_BLOCK + tid];
            int ij = sidx[j * K2_TGT_PER_BLOCK + tid];
            // lexicographic (value, index): earliest global index wins on ties
            if (mj < m || (mj == m && ij < mi)) { m = mj; mi = ij; }
        }
        out[(size_t)b * NTGT + tbase + tid] = gate[(size_t)b * NSRC + mi];
    }
}

extern "C" void kernel_launch(void* const* d_in, const int* in_sizes, int n_in,
                              void* d_out, int out_size, void* d_ws, size_t ws_size,
                              hipStream_t stream) {
    const float* sem_logits = (const float*)d_in[0];   // [B,K,NS] fp32
    const float* source_pos = (const float*)d_in[1];   // [B,3,NS] fp32
    const float* target_pos = (const float*)d_in[2];   // [B,3,NT] fp32
    float* out = (float*)d_out;                        // [B,NT,1] fp32

    // workspace layout: src4 (B*NS float4 = 256 KB) | gate (B*NS float = 64 KB)
    float4* src4 = (float4*)d_ws;
    float* gate = (float*)((char*)d_ws + sizeof(float4) * BATCH * NSRC);

    prep_kernel<<<(BATCH * NSRC) / 64, 64, 0, stream>>>(sem_logits, source_pos, src4, gate);
    nn_gate_kernel<<<BATCH * (NTGT / K2_TGT_PER_BLOCK), K2_THREADS, 0, stream>>>(
        src4, gate, target_pos, out);
}

// Round 7
// 107.451 us; speedup vs baseline: 1.7962x; 1.0416x over previous
//
#include <hip/hip_runtime.h>
#include <math.h>
#include <float.h>

// Problem constants (match reference)
#define BATCH 4
#define KCLS 16
#define NSRC 4096
#define NTGT 16384

// geometry: 512 threads = 8 waves; 2 targets/lane -> 128 targets/block;
// sources processed in 2 chunks of 2048 (32 KB LDS) -> 4 blocks/CU, 32 waves/CU
#define THREADS 512
#define WAVES 8
#define TGT_PER_BLOCK 128
#define CHUNK 2048
#define NCHUNK (NSRC / CHUNK)               // 2
#define STRIPE (CHUNK / WAVES)              // 256 sources per wave per chunk

// Single fused kernel. Bit-exact np numerics (verified absmax=0.0 R5/R6):
//   ss/tt: squares rounded individually, then sequential sum
//   dot  : rn(tx*sx); fma(ty,sy,.); fma(tz,sz,.)
//   d2   : fma(-2, dot, rn(tt+ss))   [== rn(rn(tt+ss) - rn(2*dot))]
//   gate : 1/(1+expf(-max_k logit))  computed lazily at the winning index only
__global__ __launch_bounds__(THREADS) void fused_kernel(
    const float* __restrict__ sem_logits,   // [B, K, NS]
    const float* __restrict__ source_pos,   // [B, 3, NS]
    const float* __restrict__ target_pos,   // [B, 3, NT]
    float* __restrict__ out)                // [B*NT]
{
    __shared__ float4 ls[CHUNK];            // 32 KB: chunk stage, aliased for reduce

    int tid = threadIdx.x;
    int lane = tid & 63;
    int wave = tid >> 6;                    // 0..7

    const int blocksPerBatch = NTGT / TGT_PER_BLOCK;  // 128
    int b = blockIdx.x / blocksPerBatch;
    int tbase = (blockIdx.x - b * blocksPerBatch) * TGT_PER_BLOCK;

    // two targets per lane (coalesced loads)
    const float* tp = target_pos + (size_t)b * 3 * NTGT;
    int t0 = tbase + lane, t1 = tbase + 64 + lane;
    float tx0 = tp[t0], ty0 = tp[NTGT + t0], tz0 = tp[2 * NTGT + t0];
    float tx1 = tp[t1], ty1 = tp[NTGT + t1], tz1 = tp[2 * NTGT + t1];
    float tt0 = __fadd_rn(__fadd_rn(__fmul_rn(tx0, tx0), __fmul_rn(ty0, ty0)),
                          __fmul_rn(tz0, tz0));
    float tt1 = __fadd_rn(__fadd_rn(__fmul_rn(tx1, tx1), __fmul_rn(ty1, ty1)),
                          __fmul_rn(tz1, tz1));

    const float* sx = source_pos + (size_t)b * 3 * NSRC;
    const float* sy = sx + NSRC;
    const float* sz = sx + 2 * NSRC;

    float best0 = FLT_MAX, best1 = FLT_MAX;
    int bi0 = 0, bi1 = 0;

    for (int c = 0; c < NCHUNK; ++c) {
        __syncthreads();                    // previous chunk's readers done
        // stage chunk c: 2048 sources, 4 per thread (coalesced x/y/z streams)
        int cg = c * CHUNK;
#pragma unroll
        for (int j = 0; j < CHUNK / THREADS; ++j) {
            int s = tid + j * THREADS;      // local source in chunk
            float x = sx[cg + s], y = sy[cg + s], z = sz[cg + s];
            float ss = __fadd_rn(__fadd_rn(__fmul_rn(x, x), __fmul_rn(y, y)),
                                 __fmul_rn(z, z));
            ls[s] = make_float4(x, y, z, ss);
        }
        __syncthreads();

        int lbase = wave * STRIPE;          // this wave's stripe in the chunk
        int gbase = cg + lbase;             // global index base (uniform)
#pragma unroll 8
        for (int i = 0; i < STRIPE; ++i) {
            float4 f = ls[lbase + i];       // wave-uniform -> LDS broadcast
            // target 0
            float acc0 = __fmul_rn(tx0, f.x);
            acc0 = __fmaf_rn(ty0, f.y, acc0);
            acc0 = __fmaf_rn(tz0, f.z, acc0);
            float d20 = __fmaf_rn(-2.0f, acc0, __fadd_rn(tt0, f.w));
            if (d20 < best0) { best0 = d20; bi0 = gbase + i; }  // strict '<'
            // target 1
            float acc1 = __fmul_rn(tx1, f.x);
            acc1 = __fmaf_rn(ty1, f.y, acc1);
            acc1 = __fmaf_rn(tz1, f.z, acc1);
            float d21 = __fmaf_rn(-2.0f, acc1, __fadd_rn(tt1, f.w));
            if (d21 < best1) { best1 = d21; bi1 = gbase + i; }
        }
    }

    __syncthreads();                        // all scans done before aliasing ls

    // alias ls as reduce scratch: smin[8][128] | sidx[8][128]  (8 KB)
    float* smin = (float*)ls;
    int* sidx = (int*)ls + WAVES * TGT_PER_BLOCK;
    smin[wave * TGT_PER_BLOCK + lane] = best0;
    sidx[wave * TGT_PER_BLOCK + lane] = bi0;
    smin[wave * TGT_PER_BLOCK + 64 + lane] = best1;
    sidx[wave * TGT_PER_BLOCK + 64 + lane] = bi1;
    __syncthreads();

    if (tid < TGT_PER_BLOCK) {
        float m = smin[tid];
        int mi = sidx[tid];
#pragma unroll
        for (int j = 1; j < WAVES; ++j) {
            float mj = smin[j * TGT_PER_BLOCK + tid];
            int ij = sidx[j * TGT_PER_BLOCK + tid];
            // lexicographic (value, index): earliest global index wins on ties
            if (mj < m || (mj == m && ij < mi)) { m = mj; mi = ij; }
        }
        // lazy gate at the winning index: max over K logits, then sigmoid
        const float* lg = sem_logits + (size_t)b * KCLS * NSRC + mi;
        float mm = lg[0];
#pragma unroll
        for (int k = 1; k < KCLS; ++k) mm = fmaxf(mm, lg[(size_t)k * NSRC]);
        out[(size_t)b * NTGT + tbase + tid] = 1.0f / (1.0f + expf(-mm));
    }
}

extern "C" void kernel_launch(void* const* d_in, const int* in_sizes, int n_in,
                              void* d_out, int out_size, void* d_ws, size_t ws_size,
                              hipStream_t stream) {
    const float* sem_logits = (const float*)d_in[0];   // [B,K,NS] fp32
    const float* source_pos = (const float*)d_in[1];   // [B,3,NS] fp32
    const float* target_pos = (const float*)d_in[2];   // [B,3,NT] fp32
    float* out = (float*)d_out;                        // [B,NT,1] fp32

    fused_kernel<<<BATCH * (NTGT / TGT_PER_BLOCK), THREADS, 0, stream>>>(
        sem_logits, source_pos, target_pos, out);
}

// Round 8
// 102.544 us; speedup vs baseline: 1.8822x; 1.0478x over previous
//
#include <hip/hip_runtime.h>
#include <math.h>
#include <float.h>

// Problem constants (match reference)
#define BATCH 4
#define KCLS 16
#define NSRC 4096
#define NTGT 16384

// geometry: 512 threads = 8 waves; 4 targets/lane -> 256 targets/block;
// sources split 4-ways ACROSS blocks (grid = 4*64*4 = 1024 -> 4 blocks/CU);
// each block stages its 1024-source chunk in 16 KB LDS.
#define THREADS 512
#define WAVES 8
#define TPL 4                               // targets per lane
#define TGT_PER_BLOCK 256                   // 64 lanes * TPL
#define SPLITS 4
#define CHUNK (NSRC / SPLITS)               // 1024 sources per block
#define STRIPE (CHUNK / WAVES)              // 128 iterations per wave

// Main kernel: per-(target, source-chunk) argmin partials, bit-exact np
// numerics (verified absmax=0.0 R5-R7):
//   ss/tt: squares rounded individually, then sequential sum
//   dot  : rn(tx*sx); fma(ty,sy,.); fma(tz,sz,.)
//   d2   : fma(-2, dot, rn(tt+ss))
// Cross-split combine: packed u64 atomicMin of (ordered_float(d2)<<32 | idx)
// == lexicographic (d2, first index) == np.argmin tie-break.
__global__ __launch_bounds__(THREADS, 8) void nn_partial_kernel(
    const float* __restrict__ source_pos,   // [B, 3, NS]
    const float* __restrict__ target_pos,   // [B, 3, NT]
    unsigned long long* __restrict__ ws64)  // [B*NT] packed (ord<<32)|idx
{
    __shared__ float4 ls[CHUNK];            // 16 KB stage, aliased for reduce

    int tid = threadIdx.x;
    int lane = tid & 63;
    int wave = tid >> 6;                    // 0..7

    // grid decode: blocksPerBatch = 64 tgroups * 4 splits = 256
    int b = blockIdx.x >> 8;
    int rem = blockIdx.x & 255;
    int tg = rem >> 2;
    int split = rem & 3;
    int tbase = tg * TGT_PER_BLOCK;
    int cg = split * CHUNK;                 // this block's source-chunk base

    // stage chunk: 1024 sources, 2 per thread (coalesced x/y/z streams)
    const float* sx = source_pos + (size_t)b * 3 * NSRC;
    const float* sy = sx + NSRC;
    const float* sz = sx + 2 * NSRC;
#pragma unroll
    for (int j = 0; j < CHUNK / THREADS; ++j) {
        int s = tid + j * THREADS;
        float x = sx[cg + s], y = sy[cg + s], z = sz[cg + s];
        float ss = __fadd_rn(__fadd_rn(__fmul_rn(x, x), __fmul_rn(y, y)),
                             __fmul_rn(z, z));
        ls[s] = make_float4(x, y, z, ss);
    }

    // four targets per lane: t_j = tbase + 64*j + lane (coalesced loads)
    const float* tp = target_pos + (size_t)b * 3 * NTGT;
    float tx[TPL], ty[TPL], tz[TPL], tt[TPL];
#pragma unroll
    for (int j = 0; j < TPL; ++j) {
        int t = tbase + 64 * j + lane;
        tx[j] = tp[t]; ty[j] = tp[NTGT + t]; tz[j] = tp[2 * NTGT + t];
        tt[j] = __fadd_rn(__fadd_rn(__fmul_rn(tx[j], tx[j]),
                                    __fmul_rn(ty[j], ty[j])),
                          __fmul_rn(tz[j], tz[j]));
    }

    __syncthreads();

    int lbase = wave * STRIPE;              // this wave's stripe in the chunk
    int gbase = cg + lbase;                 // global source index base (uniform)
    float best[TPL];
    int bi[TPL];
#pragma unroll
    for (int j = 0; j < TPL; ++j) { best[j] = FLT_MAX; bi[j] = 0; }

#pragma unroll 8
    for (int i = 0; i < STRIPE; ++i) {
        float4 f = ls[lbase + i];           // wave-uniform -> LDS broadcast
        int cand = gbase + i;
#pragma unroll
        for (int j = 0; j < TPL; ++j) {
            float acc = __fmul_rn(tx[j], f.x);
            acc = __fmaf_rn(ty[j], f.y, acc);
            acc = __fmaf_rn(tz[j], f.z, acc);
            float d2 = __fmaf_rn(-2.0f, acc, __fadd_rn(tt[j], f.w));
            if (d2 < best[j]) { best[j] = d2; bi[j] = cand; }  // strict '<'
        }
    }

    __syncthreads();                        // done READING ls before aliasing

    // alias ls: smin[8][256] (8 KB) | sidx[8][256] (8 KB) = 16 KB exactly
    float* smin = (float*)ls;
    int* sidx = (int*)(smin + WAVES * TGT_PER_BLOCK);
#pragma unroll
    for (int j = 0; j < TPL; ++j) {
        smin[wave * TGT_PER_BLOCK + 64 * j + lane] = best[j];
        sidx[wave * TGT_PER_BLOCK + 64 * j + lane] = bi[j];
    }
    __syncthreads();

    if (tid < TGT_PER_BLOCK) {
        float m = smin[tid];
        int mi = sidx[tid];
#pragma unroll
        for (int j = 1; j < WAVES; ++j) {
            float mj = smin[j * TGT_PER_BLOCK + tid];
            int ij = sidx[j * TGT_PER_BLOCK + tid];
            // lexicographic (value, index): earliest global index wins on ties
            if (mj < m || (mj == m && ij < mi)) { m = mj; mi = ij; }
        }
        // total-order map: monotone wrt float '<' (handles negatives)
        unsigned u = __float_as_uint(m);
        unsigned ord = (u & 0x80000000u) ? ~u : (u | 0x80000000u);
        unsigned long long packed =
            ((unsigned long long)ord << 32) | (unsigned)mi;
        atomicMin(&ws64[(size_t)b * NTGT + tbase + tid], packed);
    }
}

// Combine: extract winning index from packed u64, lazy gate gather + sigmoid.
__global__ __launch_bounds__(256) void gate_kernel(
    const unsigned long long* __restrict__ ws64,  // [B*NT]
    const float* __restrict__ sem_logits,         // [B, K, NS]
    float* __restrict__ out)                      // [B*NT]
{
    int gt = blockIdx.x * 256 + threadIdx.x;      // 0 .. B*NT-1
    int b = gt / NTGT;
    int mi = (int)(ws64[gt] & 0xFFFFFFFFull);

    const float* lg = sem_logits + (size_t)b * KCLS * NSRC + mi;
    float mm = lg[0];
#pragma unroll
    for (int k = 1; k < KCLS; ++k) mm = fmaxf(mm, lg[(size_t)k * NSRC]);
    out[gt] = 1.0f / (1.0f + expf(-mm));
}

extern "C" void kernel_launch(void* const* d_in, const int* in_sizes, int n_in,
                              void* d_out, int out_size, void* d_ws, size_t ws_size,
                              hipStream_t stream) {
    const float* sem_logits = (const float*)d_in[0];   // [B,K,NS] fp32
    const float* source_pos = (const float*)d_in[1];   // [B,3,NS] fp32
    const float* target_pos = (const float*)d_in[2];   // [B,3,NT] fp32
    float* out = (float*)d_out;                        // [B,NT,1] fp32

    unsigned long long* ws64 = (unsigned long long*)d_ws;  // 512 KB partials

    // init packed partials to u64-max (0xFF bytes)
    hipMemsetAsync(ws64, 0xFF, sizeof(unsigned long long) * BATCH * NTGT, stream);

    nn_partial_kernel<<<BATCH * (NTGT / TGT_PER_BLOCK) * SPLITS, THREADS, 0, stream>>>(
        source_pos, target_pos, ws64);
    gate_kernel<<<(BATCH * NTGT) / 256, 256, 0, stream>>>(ws64, sem_logits, out);
}

// Round 9
// 101.078 us; speedup vs baseline: 1.9095x; 1.0145x over previous
//
#include <hip/hip_runtime.h>
#include <math.h>
#include <float.h>

// Problem constants (match reference)
#define BATCH 4
#define KCLS 16
#define NSRC 4096
#define NTGT 16384

// geometry: 512 threads = 8 waves; 8 targets/lane -> 512 targets/block;
// sources split 8-ways across blocks (grid = 4*32*8 = 1024 -> 4 blocks/CU);
// each block stages its 512-source chunk in 8 KB LDS (reduce alias: 32 KB).
#define THREADS 512
#define WAVES 8
#define TPL 8                               // targets per lane
#define TGT_PER_BLOCK 512                   // 64 lanes * TPL
#define SPLITS 8
#define CHUNK (NSRC / SPLITS)               // 512 sources per block
#define STRIPE (CHUNK / WAVES)              // 64 iterations per wave

// Main kernel: per-(target, source-chunk) argmin partials, bit-exact np
// numerics (verified absmax=0.0 R5-R8):
//   ss/tt: squares rounded individually, then sequential sum
//   dot  : rn(tx*sx); fma(ty,sy,.); fma(tz,sz,.)
//   d2   : fma(-2, dot, rn(tt+ss))
// Cross-split combine: packed u64 atomicMin of (ordered_float(d2)<<32 | idx)
// == lexicographic (d2, first index) == np.argmin tie-break.
__global__ __launch_bounds__(THREADS) void nn_partial_kernel(
    const float* __restrict__ source_pos,   // [B, 3, NS]
    const float* __restrict__ target_pos,   // [B, 3, NT]
    unsigned long long* __restrict__ ws64)  // [B*NT] packed (ord<<32)|idx
{
    // 32 KB: [0,8K) source stage; aliased after the scan as
    // smin[8][512] (16 KB) | sidx[8][512] (16 KB) = 32 KB
    __shared__ float4 ls[TGT_PER_BLOCK * WAVES / 2];

    int tid = threadIdx.x;
    int lane = tid & 63;
    int wave = tid >> 6;                    // 0..7

    // grid decode: blocksPerBatch = 32 tgroups * 8 splits = 256
    int b = blockIdx.x >> 8;
    int rem = blockIdx.x & 255;
    int tg = rem >> 3;
    int split = rem & 7;
    int tbase = tg * TGT_PER_BLOCK;
    int cg = split * CHUNK;                 // this block's source-chunk base

    // stage chunk: 512 sources, 1 per thread (coalesced x/y/z streams)
    const float* sxp = source_pos + (size_t)b * 3 * NSRC;
    const float* syp = sxp + NSRC;
    const float* szp = sxp + 2 * NSRC;
    {
        int s = tid;                        // CHUNK == THREADS
        float x = sxp[cg + s], y = syp[cg + s], z = szp[cg + s];
        float ss = __fadd_rn(__fadd_rn(__fmul_rn(x, x), __fmul_rn(y, y)),
                             __fmul_rn(z, z));
        ls[s] = make_float4(x, y, z, ss);
    }

    // eight targets per lane: t_j = tbase + 64*j + lane (coalesced loads)
    const float* tp = target_pos + (size_t)b * 3 * NTGT;
    float tx[TPL], ty[TPL], tz[TPL], tt[TPL];
#pragma unroll
    for (int j = 0; j < TPL; ++j) {
        int t = tbase + 64 * j + lane;
        tx[j] = tp[t]; ty[j] = tp[NTGT + t]; tz[j] = tp[2 * NTGT + t];
        tt[j] = __fadd_rn(__fadd_rn(__fmul_rn(tx[j], tx[j]),
                                    __fmul_rn(ty[j], ty[j])),
                          __fmul_rn(tz[j], tz[j]));
    }

    __syncthreads();

    int lbase = wave * STRIPE;              // this wave's stripe in the chunk
    int gbase = cg + lbase;                 // global source index base (uniform)
    float best[TPL];
    int bi[TPL];
#pragma unroll
    for (int j = 0; j < TPL; ++j) { best[j] = FLT_MAX; bi[j] = 0; }

#pragma unroll 8
    for (int i = 0; i < STRIPE; ++i) {
        float4 f = ls[lbase + i];           // wave-uniform -> LDS broadcast
        int cand = gbase + i;
#pragma unroll
        for (int j = 0; j < TPL; ++j) {
            float acc = __fmul_rn(tx[j], f.x);
            acc = __fmaf_rn(ty[j], f.y, acc);
            acc = __fmaf_rn(tz[j], f.z, acc);
            float d2 = __fmaf_rn(-2.0f, acc, __fadd_rn(tt[j], f.w));
            if (d2 < best[j]) { best[j] = d2; bi[j] = cand; }  // strict '<'
        }
    }

    __syncthreads();                        // done READING ls before aliasing

    float* smin = (float*)ls;
    int* sidx = (int*)(smin + WAVES * TGT_PER_BLOCK);
#pragma unroll
    for (int j = 0; j < TPL; ++j) {
        smin[wave * TGT_PER_BLOCK + 64 * j + lane] = best[j];
        sidx[wave * TGT_PER_BLOCK + 64 * j + lane] = bi[j];
    }
    __syncthreads();

    {
        int t = tid;                        // TGT_PER_BLOCK == THREADS
        float m = smin[t];
        int mi = sidx[t];
#pragma unroll
        for (int j = 1; j < WAVES; ++j) {
            float mj = smin[j * TGT_PER_BLOCK + t];
            int ij = sidx[j * TGT_PER_BLOCK + t];
            // lexicographic (value, index): earliest global index wins on ties
            if (mj < m || (mj == m && ij < mi)) { m = mj; mi = ij; }
        }
        // total-order map: monotone wrt float '<' (handles negatives)
        unsigned u = __float_as_uint(m);
        unsigned ord = (u & 0x80000000u) ? ~u : (u | 0x80000000u);
        unsigned long long packed =
            ((unsigned long long)ord << 32) | (unsigned)mi;
        atomicMin(&ws64[(size_t)b * NTGT + tbase + t], packed);
    }
}

// Combine: extract winning index from packed u64, lazy gate gather + sigmoid.
__global__ __launch_bounds__(256) void gate_kernel(
    const unsigned long long* __restrict__ ws64,  // [B*NT]
    const float* __restrict__ sem_logits,         // [B, K, NS]
    float* __restrict__ out)                      // [B*NT]
{
    int gt = blockIdx.x * 256 + threadIdx.x;      // 0 .. B*NT-1
    int b = gt / NTGT;
    int mi = (int)(ws64[gt] & 0xFFFFFFFFull);

    const float* lg = sem_logits + (size_t)b * KCLS * NSRC + mi;
    float mm = lg[0];
#pragma unroll
    for (int k = 1; k < KCLS; ++k) mm = fmaxf(mm, lg[(size_t)k * NSRC]);
    out[gt] = 1.0f / (1.0f + expf(-mm));
}

extern "C" void kernel_launch(void* const* d_in, const int* in_sizes, int n_in,
                              void* d_out, int out_size, void* d_ws, size_t ws_size,
                              hipStream_t stream) {
    const float* sem_logits = (const float*)d_in[0];   // [B,K,NS] fp32
    const float* source_pos = (const float*)d_in[1];   // [B,3,NS] fp32
    const float* target_pos = (const float*)d_in[2];   // [B,3,NT] fp32
    float* out = (float*)d_out;                        // [B,NT,1] fp32

    unsigned long long* ws64 = (unsigned long long*)d_ws;  // 512 KB partials

    // init packed partials to u64-max (0xFF bytes)
    hipMemsetAsync(ws64, 0xFF, sizeof(unsigned long long) * BATCH * NTGT, stream);

    nn_partial_kernel<<<BATCH * (NTGT / TGT_PER_BLOCK) * SPLITS, THREADS, 0, stream>>>(
        source_pos, target_pos, ws64);
    gate_kernel<<<(BATCH * NTGT) / 256, 256, 0, stream>>>(ws64, sem_logits, out);
}